// Round 3
// baseline (137.928 us; speedup 1.0000x reference)
//
#include <hip/hip_runtime.h>
#include <hip/hip_bf16.h>
#include <cstdint>

// Problem constants: T=512 timesteps/slots, B=64 batch, E=512 embed.
#define TT 512
#define BB 64
#define EE 512

typedef short bf16x8 __attribute__((ext_vector_type(8)));   // 8 bf16 = 4 VGPRs
typedef float f32x4  __attribute__((ext_vector_type(4)));   // MFMA C/D frag

// RNE pack of (a -> low16, b -> high16); compiler emits v_cvt_pk_bf16_f32.
static __device__ __forceinline__ unsigned bpack(float a, float b) {
    union { __hip_bfloat162 h; unsigned u; } cv;
    cv.h = __float22bfloat162_rn(make_float2(a, b));
    return cv.u;
}

// Barrier that does NOT drain vmcnt: LDS traffic is made visible
// (lgkmcnt(0)), in-flight global register prefetches stay outstanding.
static __device__ __forceinline__ void barrier_lds_only() {
    asm volatile("s_waitcnt lgkmcnt(0)" ::: "memory");
    __builtin_amdgcn_s_barrier();
}

// ---------------------------------------------------------------------------
// V-resident design: each block owns ONE (batch b, 64-col e-slice) and ALL
// 512 m-rows. The full V slice lives in LDS as bf16 (16 chunks x [64e][32k]
// = 64 KB), so every V element is fetched from HBM exactly once (64 MB total,
// the compulsory minimum; round-2 measured 101 MB from cross-block k-prefix
// re-reads).
//
//   wave-0 prologue: queue scan (closed form, max-plus wave scan) -> Rs/CUs.
//   m-tiles mt=0..7 in order; tile mt consumes chunks kk < 2(mt+1).
//   Chunks {2mt+2,2mt+3} are packed during tile mt (global loads issued one
//   tile earlier, 2-deep register pipeline) and published by ONE barrier per
//   tile. Chunk slots are write-once: no ping-pong, no WAR hazards.
//
//   A-coeffs are computed IN REGISTERS per wave from the closed form
//   C[t,i] = clamp(R_i - cu_t,0,1) - clamp(R_{i-1} - cu_t,0,1)  (0 for i>t)
//   -- no A-tile LDS traffic, no per-kk barrier. ~3 VALU/coeff, hidden under
//   the HBM floor.
//
// 4 waves (2m x 2n): per m-tile each wave does 32m x 32n, acc[2][2].
// LDS: Vs 64 KB + Rs/CUs 4 KB = 69.6 KB -> exactly 2 blocks/CU.
// Grid: 512 blocks x 256 threads (64 b x 8 slices).
// ---------------------------------------------------------------------------
__global__ __launch_bounds__(256, 2) void queue_fused_kernel(
        const float* __restrict__ V,    // [T(i)][B][E]
        const float* __restrict__ U,    // [T][B]
        const float* __restrict__ D,    // [T][B]
        float* __restrict__ out) {      // [T(t)][B][E]
    const int id    = blockIdx.x;
    const int slice = id & 7;
    const int b     = id >> 3;
    const int n0    = slice * 64;

    __shared__ __align__(16) unsigned short Vs[16 * 2048]; // 16 x [64e][32k] bf16
    __shared__ __align__(16) float Rs[TT];
    __shared__ __align__(16) float CUs[TT];

    const int tid  = threadIdx.x;
    const int wave = tid >> 6;
    const int lane = tid & 63;

    // Stage mapping: thread owns 8k x 2e of chunk (pair*2 + c_sel).
    const int c_sel = (lane >> 5) & 1;
    const int e2    = (lane & 31) * 2;
    const int k8    = wave * 8;
    // Fragment mapping: 2x2 waves, 32m x 32n per wave per m-tile.
    const int wm   = (wave >> 1) * 32;
    const int wn   = (wave & 1) * 32;
    const int frow = lane & 15;
    const int quad = lane >> 4;

    const float* Vbase = V + (size_t)b * EE + n0 + e2;

    float2 vA[8], vB[8];                  // 2-deep global prefetch pipeline

    auto issueL = [&](float2 (&v)[8], int pair) {
        const float* p = Vbase + (size_t)((pair * 2 + c_sel) * 32 + k8) * (BB * EE);
        #pragma unroll
        for (int r = 0; r < 8; ++r)
            v[r] = *(const float2*)(p + (size_t)r * (BB * EE));
    };
    auto packW = [&](float2 (&v)[8], int pair) {
        uint4 p0, p1;
        p0.x = bpack(v[0].x, v[1].x); p0.y = bpack(v[2].x, v[3].x);
        p0.z = bpack(v[4].x, v[5].x); p0.w = bpack(v[6].x, v[7].x);
        p1.x = bpack(v[0].y, v[1].y); p1.y = bpack(v[2].y, v[3].y);
        p1.z = bpack(v[4].y, v[5].y); p1.w = bpack(v[6].y, v[7].y);
        unsigned short* dst = Vs + (pair * 2 + c_sel) * 2048 + e2 * 32 + k8;
        *(uint4*)(dst)      = p0;          // row e2
        *(uint4*)(dst + 32) = p1;          // row e2+1
    };

    // ---- Prologue ----
    // wave0's U/D loads issued FIRST: later vmcnt waits on V imply they're done.
    float su[8], sd[8];
    if (wave == 0) {
        #pragma unroll
        for (int j = 0; j < 8; ++j) {
            su[j] = U[(lane * 8 + j) * BB + b];
            sd[j] = D[(lane * 8 + j) * BB + b];
        }
    }
    issueL(vA, 0);                        // chunks {0,1}
    issueL(vB, 1);                        // chunks {2,3} -- stay in flight
    packW(vA, 0);                         // waits vA only (vmcnt(8))

    if (wave == 0) {                      // queue scan -> Rs/CUs
        float A = 0.f, Bv = -1e30f, S = 0.f;
        #pragma unroll
        for (int j = 0; j < 8; ++j) {
            const float a = sd[j] - su[j];
            Bv = fmaxf(Bv + a, sd[j]);
            A += a;
            S += su[j];
        }
        #pragma unroll
        for (int off = 1; off < 64; off <<= 1) {
            const float Ap = __shfl_up(A, off);
            const float Bp = __shfl_up(Bv, off);
            const float Sp = __shfl_up(S, off);
            if (lane >= off) {
                Bv = fmaxf(Bp + A, Bv);
                A  = A + Ap;
                S  = S + Sp;
            }
        }
        float Aex = __shfl_up(A, 1), Bex = __shfl_up(Bv, 1), Sex = __shfl_up(S, 1);
        if (lane == 0) { Aex = 0.f; Bex = -1e30f; Sex = 0.f; }
        float Q  = fmaxf(Aex, Bex);
        float cu = Sex;
        float rv[8], cv[8];
        #pragma unroll
        for (int j = 0; j < 8; ++j) {
            cu += su[j];
            Q = fmaxf(Q - su[j], 0.f) + sd[j];
            rv[j] = Q + cu;
            cv[j] = cu;
        }
        *(float4*)(Rs  + lane * 8)     = make_float4(rv[0], rv[1], rv[2], rv[3]);
        *(float4*)(Rs  + lane * 8 + 4) = make_float4(rv[4], rv[5], rv[6], rv[7]);
        *(float4*)(CUs + lane * 8)     = make_float4(cv[0], cv[1], cv[2], cv[3]);
        *(float4*)(CUs + lane * 8 + 4) = make_float4(cv[4], cv[5], cv[6], cv[7]);
    }
    barrier_lds_only();                   // publishes chunks {0,1} + Rs/CUs

    f32x4 acc[2][2];

    auto tileStep = [&](int mt, float2 (&cur)[8], float2 (&nxt)[8]) {
        // cur holds chunks {2mt+2, 2mt+3} (issued one tile ago).
        if (mt <= 5) issueL(nxt, mt + 2);  // issue-early: chunks {2mt+4,2mt+5}
        if (mt <= 6) packW(cur, mt + 1);   // write-once into fresh chunk slots

        #pragma unroll
        for (int mi = 0; mi < 2; ++mi)
            #pragma unroll
            for (int ni = 0; ni < 2; ++ni)
                acc[mi][ni] = f32x4{0.f, 0.f, 0.f, 0.f};

        const int   t0  = mt * 64 + wm + frow;   // A-row for mi=0
        const float cu0 = CUs[t0];
        const float cu1 = CUs[t0 + 16];
        const int   kkN = 2 * mt + 2;

        for (int kk = 0; kk < kkN; ++kk) {
            const int i0 = kk * 32 + quad * 8;
            // B-frags straight from resident Vs (published chunks only).
            const bf16x8 bf0 = *(const bf16x8*)(Vs + kk * 2048 + (wn + frow) * 32 + quad * 8);
            const bf16x8 bf1 = *(const bf16x8*)(Vs + kk * 2048 + (wn + 16 + frow) * 32 + quad * 8);
            // A-frags from closed form, in registers (Rs reads broadcast).
            const float4 r0 = *(const float4*)(Rs + i0);
            const float4 r1 = *(const float4*)(Rs + i0 + 4);
            const float rv[8] = {r0.x, r0.y, r0.z, r0.w, r1.x, r1.y, r1.z, r1.w};
            const float prevM = Rs[(i0 == 0) ? 0 : (i0 - 1)];
            const float prev  = (i0 == 0) ? 0.f : prevM;
            const bool  diag  = (kk >= 2 * mt);   // wave-uniform
            bf16x8 af[2];
            #pragma unroll
            for (int mi = 0; mi < 2; ++mi) {
                const float cu  = mi ? cu1 : cu0;
                const int   rel = (t0 + mi * 16) - i0;   // keep j <= rel
                float pvp = fminf(fmaxf(prev - cu, 0.f), 1.f);
                float c[8];
                #pragma unroll
                for (int j = 0; j < 8; ++j) {
                    const float pv = fminf(fmaxf(rv[j] - cu, 0.f), 1.f);
                    c[j] = pv - pvp;
                    pvp = pv;
                }
                if (diag) {
                    #pragma unroll
                    for (int j = 0; j < 8; ++j)
                        c[j] = (j <= rel) ? c[j] : 0.f;
                }
                union { uint4 u; bf16x8 v; } w;
                w.u.x = bpack(c[0], c[1]); w.u.y = bpack(c[2], c[3]);
                w.u.z = bpack(c[4], c[5]); w.u.w = bpack(c[6], c[7]);
                af[mi] = w.v;
            }
            acc[0][0] = __builtin_amdgcn_mfma_f32_16x16x32_bf16(af[0], bf0, acc[0][0], 0, 0, 0);
            acc[0][1] = __builtin_amdgcn_mfma_f32_16x16x32_bf16(af[0], bf1, acc[0][1], 0, 0, 0);
            acc[1][0] = __builtin_amdgcn_mfma_f32_16x16x32_bf16(af[1], bf0, acc[1][0], 0, 0, 0);
            acc[1][1] = __builtin_amdgcn_mfma_f32_16x16x32_bf16(af[1], bf1, acc[1][1], 0, 0, 0);
        }

        // Epilogue: C/D layout col=lane&15, row=quad*4+r (m89/m91 verified).
        #pragma unroll
        for (int mi = 0; mi < 2; ++mi)
            #pragma unroll
            for (int r = 0; r < 4; ++r) {
                const int t = mt * 64 + wm + mi * 16 + quad * 4 + r;
                float* orow = out + ((size_t)t * BB + b) * EE + n0 + wn;
                orow[frow]      = acc[mi][0][r];
                orow[16 + frow] = acc[mi][1][r];
            }

        if (mt < 7) barrier_lds_only();   // publish chunks {2mt+2,2mt+3}
    };

    for (int mt = 0; mt < 8; mt += 2) {
        tileStep(mt,     vB, vA);
        tileStep(mt + 1, vA, vB);
    }
}

extern "C" void kernel_launch(void* const* d_in, const int* in_sizes, int n_in,
                              void* d_out, int out_size, void* d_ws, size_t ws_size,
                              hipStream_t stream) {
    const float* V = (const float*)d_in[0];   // [T,B,E]
    const float* U = (const float*)d_in[1];   // [T,B]
    const float* D = (const float*)d_in[2];   // [T,B]
    float* out = (float*)d_out;               // [T,B,E]

    queue_fused_kernel<<<dim3(512), dim3(256), 0, stream>>>(V, U, D, out);
}